// Round 2
// baseline (408.579 us; speedup 1.0000x reference)
//
#include <hip/hip_runtime.h>
#include <hip/hip_cooperative_groups.h>
#include <math.h>

#define ALPHA 0.001f
#define EPS 1e-12f
#define IN_DIM 8192
#define OUT_DIM 4096
#define COL4 (IN_DIM / 4)         // 2048 float4 per row
#define NSEG 64
#define SEG_ROWS 64
#define NCC 4                     // column chunks of 2048
#define NBLK 256
#define THREADS 1024

namespace cg = cooperative_groups;

// ws layout (floats): ypart[4096*4] | y[4096] | P[64*8192] | ssq[1]
#define WS_YPART 0
#define WS_Y     (OUT_DIM * NCC)                 // 16384
#define WS_P     (WS_Y + OUT_DIM)                // 20480
#define WS_SSQ   (WS_P + NSEG * IN_DIM)          // 544768

__global__ __launch_bounds__(THREADS) void heb_fused(
    const float* __restrict__ W, const float* __restrict__ x,
    float* __restrict__ yn, float* __restrict__ Wout, float* __restrict__ ws) {
    float* ypart = ws + WS_YPART;
    float* y     = ws + WS_Y;
    float* P     = ws + WS_P;
    float* ssq   = ws + WS_SSQ;

    const int b = blockIdx.x;
    const int t = threadIdx.x;
    const int s = b >> 2;             // segment 0..63
    const int cc = b & 3;             // col chunk 0..3
    const int wave = t >> 6, lane = t & 63;

    cg::grid_group grid = cg::this_grid();

    if (b == 0 && t == 0) *ssq = 0.f;

    // ---------------- Phase 1: ypart[row][cc] = dot(W[row, chunk], x[chunk])
    {
        const float4* x4 = (const float4*)x;
        for (int rr = 0; rr < 4; ++rr) {
            const int row = s * SEG_ROWS + wave * 4 + rr;
            const float4* Wr = (const float4*)W + (size_t)row * COL4;
            float acc = 0.f;
#pragma unroll
            for (int k = 0; k < 8; ++k) {
                const int idx = cc * 512 + k * 64 + lane;
                float4 w = Wr[idx], xx = x4[idx];
                acc += w.x * xx.x + w.y * xx.y + w.z * xx.z + w.w * xx.w;
            }
#pragma unroll
            for (int off = 32; off; off >>= 1) acc += __shfl_xor(acc, off, 64);
            if (lane == 0) ypart[row * NCC + cc] = acc;
        }
    }
    grid.sync();

    // ---------------- Phase 2: y[r] = sum of 4 partials; ssq via atomics
    {
        if (t < 16) {
            const int r = b * 16 + t;
            const float v = ypart[r * NCC + 0] + ypart[r * NCC + 1] +
                            ypart[r * NCC + 2] + ypart[r * NCC + 3];
            y[r] = v;
            float q = v * v;
#pragma unroll
            for (int off = 8; off; off >>= 1) q += __shfl_xor(q, off, 64);
            if (t == 0) atomicAdd(ssq, q);
        }
    }
    grid.sync();

    // ---------------- Phase 3: y_n output; per-segment column partials (unnormalized)
    float inv;
    {
        inv = 1.f / fmaxf(sqrtf(*ssq), EPS);
        if (t < 16) {
            const int r = b * 16 + t;
            yn[r] = y[r] * inv;
        }
        const int col4 = cc * 512 + (t & 511);
        const int half = t >> 9;              // 0 or 1
        const float4* W4 = (const float4*)W;
        const int j0 = s * SEG_ROWS + half * 32;
        float4 acc = make_float4(0.f, 0.f, 0.f, 0.f);
#pragma unroll 4
        for (int j = 0; j < 32; ++j) {
            const float yj = y[j0 + j];
            float4 w = W4[(size_t)(j0 + j) * COL4 + col4];
            acc.x += w.x * yj; acc.y += w.y * yj;
            acc.z += w.z * yj; acc.w += w.w * yj;
        }
        __shared__ float4 comb[512];
        if (half == 1) comb[t & 511] = acc;
        __syncthreads();
        if (half == 0) {
            const float4 o = comb[t & 511];
            acc.x += o.x; acc.y += o.y; acc.z += o.z; acc.w += o.w;
            ((float4*)P)[(size_t)s * COL4 + col4] = acc;
        }
    }
    grid.sync();

    // ---------------- Phase 4: exclusive scan of P over segments (in place)
    if (b < 128 && t < 16) {
        const int col4 = b * 16 + t;
        float4* P4 = (float4*)P;
        float4 run = make_float4(0.f, 0.f, 0.f, 0.f);
#pragma unroll 8
        for (int ss = 0; ss < NSEG; ++ss) {
            const float4 v = P4[(size_t)ss * COL4 + col4];
            P4[(size_t)ss * COL4 + col4] = run;
            run.x += v.x; run.y += v.y; run.z += v.z; run.w += v.w;
        }
    }
    grid.sync();

    // ---------------- Phase 5: local inclusive scan + Sanger update
    {
        const int c0 = cc * 2048 + t;          // this thread's 2 columns: c0, c0+1024
        const float a_scale = ALPHA * inv;     // α·inv   (aj = α·yv_j)
        const float b_scale = ALPHA * inv * inv;
        const int j0 = s * SEG_ROWS;
        float run0 = P[(size_t)s * IN_DIM + c0];
        float run1 = P[(size_t)s * IN_DIM + c0 + 1024];
        const float xc0 = x[c0], xc1 = x[c0 + 1024];
#pragma unroll 4
        for (int j = 0; j < SEG_ROWS; ++j) {
            const float yj = y[j0 + j];
            const float aj = a_scale * yj;
            const float bj = b_scale * yj;
            const size_t i0 = (size_t)(j0 + j) * IN_DIM + c0;
            const float w0 = W[i0], w1 = W[i0 + 1024];
            run0 += w0 * yj;
            run1 += w1 * yj;
            Wout[i0]        = w0 + aj * xc0 - bj * run0;
            Wout[i0 + 1024] = w1 + aj * xc1 - bj * run1;
        }
    }
}

extern "C" void kernel_launch(void* const* d_in, const int* in_sizes, int n_in,
                              void* d_out, int out_size, void* d_ws, size_t ws_size,
                              hipStream_t stream) {
    const float* x = (const float*)d_in[0];   // [8192]
    const float* W = (const float*)d_in[1];   // [4096, 8192]
    float* out = (float*)d_out;
    float* yn = out;                          // [4096]
    float* Wout = out + OUT_DIM;              // [4096*8192]
    float* ws = (float*)d_ws;

    void* args[] = {(void*)&W, (void*)&x, (void*)&yn, (void*)&Wout, (void*)&ws};
    hipLaunchCooperativeKernel((const void*)heb_fused, dim3(NBLK), dim3(THREADS),
                               args, 0, stream);
}

// Round 4
// 284.515 us; speedup vs baseline: 1.4361x; 1.4361x over previous
//
#include <hip/hip_runtime.h>
#include <math.h>

#define ALPHA 0.001f
#define EPS 1e-12f
#define IN_DIM 8192
#define OUT_DIM 4096
#define COL4 (IN_DIM / 4)         // 2048 float4 per row
#define NSEG 128
#define SEG_ROWS (OUT_DIM / NSEG) // 32

typedef float f32x4 __attribute__((ext_vector_type(4)));

// ---------------- Kernel 1: y = W @ x (unnormalized), one wave per row ----
__global__ __launch_bounds__(256) void k_matvec(const float* __restrict__ W,
                                                const float* __restrict__ x,
                                                float* __restrict__ y) {
    const int wave = threadIdx.x >> 6;
    const int lane = threadIdx.x & 63;
    const int row = blockIdx.x * 4 + wave;
    const float4* Wr = (const float4*)(W + (size_t)row * IN_DIM);
    const float4* xv = (const float4*)x;
    float acc = 0.0f;
#pragma unroll 8
    for (int c = 0; c < COL4 / 64; ++c) {       // 32 float4 per lane
        float4 w = Wr[lane + c * 64];
        float4 xx = xv[lane + c * 64];
        acc += w.x * xx.x + w.y * xx.y + w.z * xx.z + w.w * xx.w;
    }
#pragma unroll
    for (int off = 32; off; off >>= 1) acc += __shfl_xor(acc, off, 64);
    if (lane == 0) y[row] = acc;
}

// ---------------- Kernel 2: normalize; write y_n to out, yv to ws ---------
__global__ __launch_bounds__(256) void k_norm(const float* __restrict__ y,
                                              float* __restrict__ yn_out,
                                              float* __restrict__ yv_ws) {
    __shared__ float red[4];
    float s = 0.0f;
    for (int i = threadIdx.x; i < OUT_DIM; i += 256) {
        float v = y[i];
        s += v * v;
    }
#pragma unroll
    for (int off = 32; off; off >>= 1) s += __shfl_xor(s, off, 64);
    const int wave = threadIdx.x >> 6;
    const int lane = threadIdx.x & 63;
    if (lane == 0) red[wave] = s;
    __syncthreads();
    const float tot = red[0] + red[1] + red[2] + red[3];
    const float inv = 1.0f / fmaxf(sqrtf(tot), EPS);
    for (int i = threadIdx.x; i < OUT_DIM; i += 256) {
        float v = y[i] * inv;
        yn_out[i] = v;
        yv_ws[i] = v;
    }
}

// ---------------- Kernel 3: per-segment column sums P[s][i] ---------------
// grid: (COL4/256 = 8, NSEG=128); block 256; 1 float4-col per thread
__global__ __launch_bounds__(256) void k_pseg(const float* __restrict__ W,
                                              const float* __restrict__ yv,
                                              float* __restrict__ P) {
    const int seg = blockIdx.y;
    const int col4 = blockIdx.x * 256 + threadIdx.x;  // 0..COL4-1
    const float4* Wp = (const float4*)W;
    const int j0 = seg * SEG_ROWS;
    float4 acc = make_float4(0.f, 0.f, 0.f, 0.f);
#pragma unroll 4
    for (int j = 0; j < SEG_ROWS; ++j) {
        const float yj = yv[j0 + j];
        float4 w = Wp[(size_t)(j0 + j) * COL4 + col4];
        acc.x += w.x * yj;
        acc.y += w.y * yj;
        acc.z += w.z * yj;
        acc.w += w.w * yj;
    }
    ((float4*)P)[(size_t)seg * COL4 + col4] = acc;
}

// ---------------- Kernel 4: exclusive scan of P over segments, in place ---
// grid: 32 blocks x 64 threads = 2048 threads, one float4-col each
__global__ __launch_bounds__(64) void k_scan(float* __restrict__ P) {
    const int col4 = blockIdx.x * 64 + threadIdx.x;
    float4* Pp = (float4*)P;
    float4 run = make_float4(0.f, 0.f, 0.f, 0.f);
#pragma unroll 8
    for (int s = 0; s < NSEG; ++s) {
        float4 v = Pp[(size_t)s * COL4 + col4];
        Pp[(size_t)s * COL4 + col4] = run;
        run.x += v.x;
        run.y += v.y;
        run.z += v.z;
        run.w += v.w;
    }
}

// ---------------- Kernel 5: local inclusive scan + Hebbian update ---------
// grid: (COL4/512 = 4, NSEG=128); block 512; 1 float4-col per thread
__global__ __launch_bounds__(512) void k_update(const float* __restrict__ W,
                                                const float* __restrict__ x,
                                                const float* __restrict__ yv,
                                                const float* __restrict__ E,
                                                float* __restrict__ Wout) {
    const int seg = blockIdx.y;
    const int col4 = blockIdx.x * 512 + threadIdx.x;
    const float4* Wp = (const float4*)W;
    f32x4* Op = (f32x4*)Wout;
    float4 run = ((const float4*)E)[(size_t)seg * COL4 + col4];
    const float4 x4 = ((const float4*)x)[col4];
    const int j0 = seg * SEG_ROWS;
#pragma unroll 4
    for (int j = 0; j < SEG_ROWS; ++j) {
        const float yj = yv[j0 + j];
        const float aj = ALPHA * yj;
        const size_t idx = (size_t)(j0 + j) * COL4 + col4;
        float4 w = Wp[idx];
        run.x += w.x * yj;
        run.y += w.y * yj;
        run.z += w.z * yj;
        run.w += w.w * yj;
        f32x4 o;
        o.x = w.x + aj * (x4.x - run.x);
        o.y = w.y + aj * (x4.y - run.y);
        o.z = w.z + aj * (x4.z - run.z);
        o.w = w.w + aj * (x4.w - run.w);
        __builtin_nontemporal_store(o, &Op[idx]);
    }
}

extern "C" void kernel_launch(void* const* d_in, const int* in_sizes, int n_in,
                              void* d_out, int out_size, void* d_ws, size_t ws_size,
                              hipStream_t stream) {
    const float* x = (const float*)d_in[0];   // [8192]
    const float* W = (const float*)d_in[1];   // [4096, 8192]
    float* out = (float*)d_out;
    float* yn_out = out;                      // [4096]
    float* Wout = out + OUT_DIM;              // [4096*8192]

    // workspace layout (floats): y/yv [4096] | P [NSEG*IN_DIM = 1M]
    float* y = (float*)d_ws;
    float* P = y + OUT_DIM;

    // 1. y = W @ x
    k_matvec<<<dim3(OUT_DIM / 4), dim3(256), 0, stream>>>(W, x, y);
    // 2. normalize (yv overwrites y in ws; also written to d_out)
    k_norm<<<dim3(1), dim3(256), 0, stream>>>(y, yn_out, y);
    // 3. per-segment partial column sums
    k_pseg<<<dim3(COL4 / 256, NSEG), dim3(256), 0, stream>>>(W, y, P);
    // 4. exclusive scan over segments (in place)
    k_scan<<<dim3(32), dim3(64), 0, stream>>>(P);
    // 5. local scan + update (nontemporal Wout stores keep W L3-resident)
    k_update<<<dim3(COL4 / 512, NSEG), dim3(512), 0, stream>>>(W, x, y, P, Wout);
}